// Round 18
// baseline (1377.069 us; speedup 1.0000x reference)
//
#include <hip/hip_runtime.h>

#define Bsz  256
#define Tlen 2048
#define Hdim 128

typedef __fp16 hf2 __attribute__((ext_vector_type(2)));
typedef __fp16 hf8 __attribute__((ext_vector_type(8)));
typedef float  f32x4 __attribute__((ext_vector_type(4)));

// Raw-HW transcendentals (VOP1, ~1 ulp). R12-verified win.
__device__ __forceinline__ float fexp2_(float x) {
    float r; asm("v_exp_f32 %0, %1" : "=v"(r) : "v"(x)); return r;
}
__device__ __forceinline__ float frcp_(float x) {
    float r; asm("v_rcp_f32 %0, %1" : "=v"(r) : "v"(x)); return r;
}
__device__ __forceinline__ float sigmoidf_(float v) {
    return frcp_(1.0f + fexp2_(v * -1.44269504f));
}
__device__ __forceinline__ float tanhf_(float v) {
    return 1.0f - 2.0f * frcp_(fexp2_(v * 2.88539008f) + 1.0f);
}

// pack 8 consecutive f32 into a v8f16 MFMA fragment slice
__device__ __forceinline__ hf8 pack8(const float* p) {
    union { hf2 h2[4]; hf8 h8; } u;
    u.h2[0] = __builtin_amdgcn_cvt_pkrtz(p[0], p[1]);
    u.h2[1] = __builtin_amdgcn_cvt_pkrtz(p[2], p[3]);
    u.h2[2] = __builtin_amdgcn_cvt_pkrtz(p[4], p[5]);
    u.h2[3] = __builtin_amdgcn_cvt_pkrtz(p[6], p[7]);
    return u.h8;
}

#define MFMA(D, A, B) D = __builtin_amdgcn_mfma_f32_16x16x32_f16(A, B, D, 0, 0, 0)

// grid = 256 blocks (1 batch row each), block = 512 threads (8 waves).
// R18: MFMA restructure. gh[385] = W'[385x128] . h[128] as 25 row-tiles x
// 4 K-chunks of v_mfma_f32_16x16x32_f16. Wave w owns tiles {w, w+8, w+16, 24}
// (tile 24 = Wfc row + zero pad, redundantly computed by all waves — benign
// identical-data LDS writes). A-fragments live in AGPRs and are read NATIVELY
// by MFMA — eliminating the ~115/wave/step v_accvgpr_read churn that R7-R17
// proved unremovable for VOP-based dots (VOP can't read AGPRs; R8 HW-proven).
// B trick: h is replicated across all 16 B-columns (B[k][n] = h[k] for all n),
// so every D column equals gh and no column masking is needed.
// Layouts (m89/m120 HW-verified): A[row=tile*16+(l&15)][k=c*32+(l>>4)*8+j];
// D: lane l reg r -> row (l>>4)*4+r (col = l&15, all equal).
__global__ __launch_bounds__(512, 2)
void rnn_imp_kernel(const float* __restrict__ x,     // [B, T] (I=1)
                    const float* __restrict__ Wih,   // [384]
                    const float* __restrict__ Whh,   // [384, 128] gate-major (r,z,n)
                    const float* __restrict__ bih,   // [384]
                    const float* __restrict__ bhh,   // [384]
                    const float* __restrict__ Wfc,   // [128]
                    const float* __restrict__ bfc,   // [1]
                    float* __restrict__ out_newin,   // [T, B]
                    float* __restrict__ out_pred)    // [B, T-1]
{
    __shared__ __align__(16) float  x_s[Tlen + 4];
    __shared__ __align__(16) float  xh_s[Tlen + 4];
    __shared__ __align__(16) __fp16 h16[Hdim];      // single buffer (2-barrier phases)
    __shared__ __align__(16) float  gh[400];        // 25 tiles x 16 rows

    const int tid  = threadIdx.x;
    const int b    = blockIdx.x;
    const int wave = tid >> 6;
    const int lane = tid & 63;
    const int m    = lane & 15;      // row-in-tile (A) / column (B,D)
    const int q    = lane >> 4;      // k-subchunk (A,B) / row-quad (D)

    // stage x row (coalesced) and zero h
    for (int i = tid; i < Tlen; i += 512) x_s[i] = x[b * Tlen + i];
    if (tid < Hdim) h16[tid] = (__fp16)0.0f;

    // ---- A fragments (load once; consumed only by MFMA -> AGPR-resident) ----
    const int r0 = wave * 16 + m;            // tile w    : rows 0..127   (Whh r)
    const int r1 = r0 + 128;                 // tile w+8  : rows 128..255 (Whh z)
    const int r2 = r0 + 256;                 // tile w+16 : rows 256..383 (Whh n)
    hf8 A00, A01, A02, A03;                  // [chunk c]
    hf8 A10, A11, A12, A13;
    hf8 A20, A21, A22, A23;
    hf8 A30, A31, A32, A33;                  // tile 24: row 384 = Wfc, 385+ = 0
    A00 = pack8(Whh + r0 * Hdim + 0);   A01 = pack8(Whh + r0 * Hdim + 32);
    A02 = pack8(Whh + r0 * Hdim + 64);  A03 = pack8(Whh + r0 * Hdim + 96);
    A10 = pack8(Whh + r1 * Hdim + 0);   A11 = pack8(Whh + r1 * Hdim + 32);
    A12 = pack8(Whh + r1 * Hdim + 64);  A13 = pack8(Whh + r1 * Hdim + 96);
    A20 = pack8(Whh + r2 * Hdim + 0);   A21 = pack8(Whh + r2 * Hdim + 32);
    A22 = pack8(Whh + r2 * Hdim + 64);  A23 = pack8(Whh + r2 * Hdim + 96);
    {
        const hf8 zz = hf8{0,0,0,0,0,0,0,0};
        A30 = (m == 0) ? pack8(Wfc + 0)  : zz;
        A31 = (m == 0) ? pack8(Wfc + 32) : zz;
        A32 = (m == 0) ? pack8(Wfc + 64) : zz;
        A33 = (m == 0) ? pack8(Wfc + 96) : zz;
    }
    // A-fragment k-offset: k = c*32 + q*8 + j  -> pointer + q*8 applied here:
    // (adjusting above loads) — fold q*8 into the base via lane arithmetic:
    // NOTE: loads above intentionally omit q*8; corrected by re-packing below.
    // To keep it simple and correct, redo with q offset:
    A00 = pack8(Whh + r0 * Hdim + 0  + q * 8);  A01 = pack8(Whh + r0 * Hdim + 32 + q * 8);
    A02 = pack8(Whh + r0 * Hdim + 64 + q * 8);  A03 = pack8(Whh + r0 * Hdim + 96 + q * 8);
    A10 = pack8(Whh + r1 * Hdim + 0  + q * 8);  A11 = pack8(Whh + r1 * Hdim + 32 + q * 8);
    A12 = pack8(Whh + r1 * Hdim + 64 + q * 8);  A13 = pack8(Whh + r1 * Hdim + 96 + q * 8);
    A20 = pack8(Whh + r2 * Hdim + 0  + q * 8);  A21 = pack8(Whh + r2 * Hdim + 32 + q * 8);
    A22 = pack8(Whh + r2 * Hdim + 64 + q * 8);  A23 = pack8(Whh + r2 * Hdim + 96 + q * 8);
    {
        const hf8 zz = hf8{0,0,0,0,0,0,0,0};
        A30 = (m == 0) ? pack8(Wfc + 0  + q * 8) : zz;
        A31 = (m == 0) ? pack8(Wfc + 32 + q * 8) : zz;
        A32 = (m == 0) ? pack8(Wfc + 64 + q * 8) : zz;
        A33 = (m == 0) ? pack8(Wfc + 96 + q * 8) : zz;
    }

    // gate constants for phase-2 lanes (tid < 128); clamped index keeps
    // loads in-bounds for all threads, values unused by tid >= 128
    const int ug = tid & 127;
    const float wih_r = Wih[ug], wih_z = Wih[ug + 128], wih_n = Wih[ug + 256];
    const float bb_r = bih[ug]       + bhh[ug];
    const float bb_z = bih[ug + 128] + bhh[ug + 128];
    const float bi_n = bih[ug + 256];
    const float bh_n = bhh[ug + 256];
    const float bfc0 = bfc[0];
    float h_old = 0.0f;

    const int gw0 = wave * 16 + q * 4;       // gh write bases (m==0 lanes)
    const int gw3 = 24 * 16 + q * 4;

    __syncthreads();

#pragma unroll 1
    for (int t = 0; t < Tlen; ++t) {
        // ---- phase 1: B fragments + 16 MFMAs + gh writes ----
        // B[k][n] = h[k] for all n: lane reads h16[c*32 + q*8 .. +7]
        const float4* hp = (const float4*)h16;
        hf8 B0 = __builtin_bit_cast(hf8, hp[0 * 4 + q]);
        hf8 B1 = __builtin_bit_cast(hf8, hp[1 * 4 + q]);
        hf8 B2 = __builtin_bit_cast(hf8, hp[2 * 4 + q]);
        hf8 B3 = __builtin_bit_cast(hf8, hp[3 * 4 + q]);

        f32x4 D0 = {0.f, 0.f, 0.f, 0.f};
        f32x4 D1 = {0.f, 0.f, 0.f, 0.f};
        f32x4 D2 = {0.f, 0.f, 0.f, 0.f};
        f32x4 D3 = {0.f, 0.f, 0.f, 0.f};
        MFMA(D0, A00, B0); MFMA(D1, A10, B0); MFMA(D2, A20, B0); MFMA(D3, A30, B0);
        MFMA(D0, A01, B1); MFMA(D1, A11, B1); MFMA(D2, A21, B1); MFMA(D3, A31, B1);
        MFMA(D0, A02, B2); MFMA(D1, A12, B2); MFMA(D2, A22, B2); MFMA(D3, A32, B2);
        MFMA(D0, A03, B3); MFMA(D1, A13, B3); MFMA(D2, A23, B3); MFMA(D3, A33, B3);

        if (m == 0) {   // columns are replicas; col-0 lanes write 4 rows each
            *(f32x4*)(gh + gw0)       = D0;
            *(f32x4*)(gh + gw0 + 128) = D1;
            *(f32x4*)(gh + gw0 + 256) = D2;
            *(f32x4*)(gh + gw3)       = D3;   // 8 waves, identical data: benign
        }
        __syncthreads();

        // ---- phase 2: gates on waves 0-1 (lane = unit) ----
        if (tid < Hdim) {
            const int u = tid;
            float ghr = gh[u], ghz = gh[u + 128], ghn = gh[u + 256];
            float xp  = gh[384];
            float xt  = x_s[t];
            float xh  = xp + bfc0;
            float cur = ((xt == 128.0f) && (t != 0)) ? xh : xt;

            float r  = sigmoidf_(wih_r * cur + bb_r + ghr);
            float z  = sigmoidf_(wih_z * cur + bb_z + ghz);
            float n  = tanhf_(wih_n * cur + bi_n + r * (ghn + bh_n));
            float hn = (1.0f - z) * n + z * h_old;
            h_old = hn;

            h16[u] = (__fp16)hn;
            if (u == 0) xh_s[t] = xh;
        }
        __syncthreads();
    }

    // bulk flush; cur reconstructed from pristine x_s + xh_s
    for (int i = tid; i < Tlen; i += 512) {
        float xv = x_s[i];
        float cv = ((xv == 128.0f) && (i != 0)) ? xh_s[i] : xv;
        out_newin[i * Bsz + b] = cv;
    }
    for (int i = tid; i < Tlen - 1; i += 512)
        out_pred[b * (Tlen - 1) + i] = xh_s[i + 1];
}

extern "C" void kernel_launch(void* const* d_in, const int* in_sizes, int n_in,
                              void* d_out, int out_size, void* d_ws, size_t ws_size,
                              hipStream_t stream) {
    const float* x   = (const float*)d_in[0];
    const float* Wih = (const float*)d_in[1];
    const float* Whh = (const float*)d_in[2];
    const float* bih = (const float*)d_in[3];
    const float* bhh = (const float*)d_in[4];
    const float* Wfc = (const float*)d_in[5];
    const float* bfc = (const float*)d_in[6];

    float* out_newin = (float*)d_out;                 // [T*B] = 524288
    float* out_pred  = out_newin + Tlen * Bsz;        // [B*(T-1)] = 524032

    rnn_imp_kernel<<<Bsz, 512, 0, stream>>>(x, Wih, Whh, bih, bhh, Wfc, bfc,
                                            out_newin, out_pred);
}

// Round 19
// 1125.571 us; speedup vs baseline: 1.2234x; 1.2234x over previous
//
#include <hip/hip_runtime.h>

#define Bsz  256
#define Tlen 2048
#define Hdim 128

typedef __fp16 hf2 __attribute__((ext_vector_type(2)));
typedef __fp16 hf8 __attribute__((ext_vector_type(8)));
typedef float  f32x4 __attribute__((ext_vector_type(4)));

// Raw-HW transcendentals (VOP1, ~1 ulp). R12-verified win.
__device__ __forceinline__ float fexp2_(float x) {
    float r; asm("v_exp_f32 %0, %1" : "=v"(r) : "v"(x)); return r;
}
__device__ __forceinline__ float frcp_(float x) {
    float r; asm("v_rcp_f32 %0, %1" : "=v"(r) : "v"(x)); return r;
}
__device__ __forceinline__ float sigmoidf_(float v) {
    return frcp_(1.0f + fexp2_(v * -1.44269504f));
}
__device__ __forceinline__ float tanhf_(float v) {
    return 1.0f - 2.0f * frcp_(fexp2_(v * 2.88539008f) + 1.0f);
}

// pack 8 consecutive f32 into a v8f16 MFMA fragment slice
__device__ __forceinline__ hf8 pack8(const float* p) {
    union { hf2 h2[4]; hf8 h8; } u;
    u.h2[0] = __builtin_amdgcn_cvt_pkrtz(p[0], p[1]);
    u.h2[1] = __builtin_amdgcn_cvt_pkrtz(p[2], p[3]);
    u.h2[2] = __builtin_amdgcn_cvt_pkrtz(p[4], p[5]);
    u.h2[3] = __builtin_amdgcn_cvt_pkrtz(p[6], p[7]);
    return u.h8;
}

#define MFMA(D, A, B) D = __builtin_amdgcn_mfma_f32_16x16x32_f16(A, B, D, 0, 0, 0)

// grid = 256 blocks (1 batch row each), block = 512 threads (8 waves).
// R19: operand-inverted MFMA. A = h on row 0 only (rows 1-15 zero via a
// zero-region LDS address select — loop-invariant per lane except parity);
// B = W^T (lane l reg j = W[w*16 + (l&15)][c*32 + (l>>4)*8 + j] — byte-identical
// loads to R18's A fragments, which HW-validated the layout). Then
// D[0][col] = gh[w*16+col] lands in lanes 0-15 reg 0: each wave holds the r/z/n
// pre-activations + xp for ITS 16 units in registers. Gates run in-wave
// (lane = unit, no redundancy), h_old stays in lane registers, 16 f16 h-writes,
// ONE barrier/step. No gh LDS array, no second barrier, no idle-wave gate phase
// (R18's three structural costs). Weights consumed only by MFMA -> AGPR-native.
__global__ __launch_bounds__(512, 2)
void rnn_imp_kernel(const float* __restrict__ x,     // [B, T] (I=1)
                    const float* __restrict__ Wih,   // [384]
                    const float* __restrict__ Whh,   // [384, 128] gate-major (r,z,n)
                    const float* __restrict__ bih,   // [384]
                    const float* __restrict__ bhh,   // [384]
                    const float* __restrict__ Wfc,   // [128]
                    const float* __restrict__ bfc,   // [1]
                    float* __restrict__ out_newin,   // [T, B]
                    float* __restrict__ out_pred)    // [B, T-1]
{
    __shared__ __align__(16) float  x_s[Tlen + 4];
    __shared__ __align__(16) float  xh_s[Tlen + 4];
    __shared__ __align__(16) __fp16 hbuf[2][Hdim];  // double-buffered h (256 B each)
    __shared__ __align__(16) __fp16 zbuf[Hdim];     // 256 B of zeros (A rows 1-15)

    const int tid  = threadIdx.x;
    const int b    = blockIdx.x;
    const int wave = tid >> 6;
    const int lane = tid & 63;
    const int m    = lane & 15;      // B/D column = unit-in-tile; A row
    const int q    = lane >> 4;      // k-subchunk

    // stage x row (coalesced); zero h buffer 0 and the zero region
    for (int i = tid; i < Tlen; i += 512) x_s[i] = x[b * Tlen + i];
    if (tid < Hdim) hbuf[0][tid] = (__fp16)0.0f;
    if (tid < Hdim) zbuf[tid]    = (__fp16)0.0f;

    // ---- B fragments: W^T tiles (consumed only by MFMA -> AGPR-resident) ----
    const int r0 = wave * 16 + m;            // unit row for gate r
    const int r1 = r0 + 128;                 // gate z
    const int r2 = r0 + 256;                 // gate n
    const int ko = q * 8;                    // k-offset within chunk
    hf8 Br0, Br1, Br2, Br3, Bz0, Bz1, Bz2, Bz3,
        Bn0, Bn1, Bn2, Bn3, Bf0, Bf1, Bf2, Bf3;
    Br0 = pack8(Whh + r0 * Hdim + 0  + ko);  Br1 = pack8(Whh + r0 * Hdim + 32 + ko);
    Br2 = pack8(Whh + r0 * Hdim + 64 + ko);  Br3 = pack8(Whh + r0 * Hdim + 96 + ko);
    Bz0 = pack8(Whh + r1 * Hdim + 0  + ko);  Bz1 = pack8(Whh + r1 * Hdim + 32 + ko);
    Bz2 = pack8(Whh + r1 * Hdim + 64 + ko);  Bz3 = pack8(Whh + r1 * Hdim + 96 + ko);
    Bn0 = pack8(Whh + r2 * Hdim + 0  + ko);  Bn1 = pack8(Whh + r2 * Hdim + 32 + ko);
    Bn2 = pack8(Whh + r2 * Hdim + 64 + ko);  Bn3 = pack8(Whh + r2 * Hdim + 96 + ko);
    {   // Wfc tile: col 0 = Wfc, cols 1-15 = 0  ->  D3[0][0] = xp
        const hf8 zz = hf8{0,0,0,0,0,0,0,0};
        Bf0 = (m == 0) ? pack8(Wfc + 0  + ko) : zz;
        Bf1 = (m == 0) ? pack8(Wfc + 32 + ko) : zz;
        Bf2 = (m == 0) ? pack8(Wfc + 64 + ko) : zz;
        Bf3 = (m == 0) ? pack8(Wfc + 96 + ko) : zz;
    }

    // gate constants for this wave's unit (lanes 0-15; clamped index for others)
    const int ug = wave * 16 + m;            // unit = w*16 + m
    const float wih_r = Wih[ug], wih_z = Wih[ug + 128], wih_n = Wih[ug + 256];
    const float bb_r = bih[ug]       + bhh[ug];
    const float bb_z = bih[ug + 128] + bhh[ug + 128];
    const float bi_n = bih[ug + 256];
    const float bh_n = bhh[ug + 256];
    const float bfc0 = bfc[0];
    float h_old = 0.0f;                      // lanes 0-15: unit ug's hidden state

    __syncthreads();

#pragma unroll 1
    for (int t = 0; t < Tlen; ++t) {
        // ---- A fragments: h on row 0 (m==0 lanes), zeros elsewhere ----
        const __fp16* hsel = (m == 0) ? hbuf[t & 1] : zbuf;
        const float4* hp = (const float4*)hsel;
        hf8 A0 = __builtin_bit_cast(hf8, hp[0 * 4 + q]);
        hf8 A1 = __builtin_bit_cast(hf8, hp[1 * 4 + q]);
        hf8 A2 = __builtin_bit_cast(hf8, hp[2 * 4 + q]);
        hf8 A3 = __builtin_bit_cast(hf8, hp[3 * 4 + q]);

        f32x4 D0 = {0.f, 0.f, 0.f, 0.f};    // ghr for units w*16+col
        f32x4 D1 = {0.f, 0.f, 0.f, 0.f};    // ghz
        f32x4 D2 = {0.f, 0.f, 0.f, 0.f};    // ghn
        f32x4 D3 = {0.f, 0.f, 0.f, 0.f};    // xp in [0][0]
        MFMA(D0, A0, Br0); MFMA(D1, A0, Bz0); MFMA(D2, A0, Bn0); MFMA(D3, A0, Bf0);
        MFMA(D0, A1, Br1); MFMA(D1, A1, Bz1); MFMA(D2, A1, Bn1); MFMA(D3, A1, Bf1);
        MFMA(D0, A2, Br2); MFMA(D1, A2, Bz2); MFMA(D2, A2, Bn2); MFMA(D3, A2, Bf2);
        MFMA(D0, A3, Br3); MFMA(D1, A3, Bz3); MFMA(D2, A3, Bn3); MFMA(D3, A3, Bf3);

        // xp lives in lane 0 reg 0 (row 0, col 0) -> broadcast to all lanes
        float xp  = __builtin_amdgcn_readfirstlane(D3[0]);
        float xh  = xp + bfc0;
        float xt  = x_s[t];
        float cur = ((xt == 128.0f) && (t != 0)) ? xh : xt;

        // gates on lanes 0-15 (q==0): reg 0 = row 0 = the gh row
        if (lane < 16) {
            float r  = sigmoidf_(wih_r * cur + bb_r + D0[0]);
            float z  = sigmoidf_(wih_z * cur + bb_z + D1[0]);
            float n  = tanhf_(wih_n * cur + bi_n + r * (D2[0] + bh_n));
            float hn = (1.0f - z) * n + z * h_old;
            h_old = hn;
            hbuf[(t + 1) & 1][ug] = (__fp16)hn;   // 16 consecutive b16/wave
        }
        if (tid == 0) xh_s[t] = xh;
        __syncthreads();
    }

    // bulk flush; cur reconstructed from pristine x_s + xh_s
    for (int i = tid; i < Tlen; i += 512) {
        float xv = x_s[i];
        float cv = ((xv == 128.0f) && (i != 0)) ? xh_s[i] : xv;
        out_newin[i * Bsz + b] = cv;
    }
    for (int i = tid; i < Tlen - 1; i += 512)
        out_pred[b * (Tlen - 1) + i] = xh_s[i + 1];
}

extern "C" void kernel_launch(void* const* d_in, const int* in_sizes, int n_in,
                              void* d_out, int out_size, void* d_ws, size_t ws_size,
                              hipStream_t stream) {
    const float* x   = (const float*)d_in[0];
    const float* Wih = (const float*)d_in[1];
    const float* Whh = (const float*)d_in[2];
    const float* bih = (const float*)d_in[3];
    const float* bhh = (const float*)d_in[4];
    const float* Wfc = (const float*)d_in[5];
    const float* bfc = (const float*)d_in[6];

    float* out_newin = (float*)d_out;                 // [T*B] = 524288
    float* out_pred  = out_newin + Tlen * Bsz;        // [B*(T-1)] = 524032

    rnn_imp_kernel<<<Bsz, 512, 0, stream>>>(x, Wih, Whh, bih, bhh, Wfc, bfc,
                                            out_newin, out_pred);
}

// Round 20
// 1026.661 us; speedup vs baseline: 1.3413x; 1.0963x over previous
//
#include <hip/hip_runtime.h>

#define Bsz  256
#define Tlen 2048
#define Hdim 128

typedef __fp16 hf2 __attribute__((ext_vector_type(2)));
typedef __fp16 hf8 __attribute__((ext_vector_type(8)));
typedef float  f32x4 __attribute__((ext_vector_type(4)));

// Raw-HW transcendentals (VOP1, ~1 ulp). R12-verified win.
__device__ __forceinline__ float fexp2_(float x) {
    float r; asm("v_exp_f32 %0, %1" : "=v"(r) : "v"(x)); return r;
}
__device__ __forceinline__ float frcp_(float x) {
    float r; asm("v_rcp_f32 %0, %1" : "=v"(r) : "v"(x)); return r;
}
__device__ __forceinline__ float sigmoidf_(float v) {
    return frcp_(1.0f + fexp2_(v * -1.44269504f));
}
__device__ __forceinline__ float tanhf_(float v) {
    return 1.0f - 2.0f * frcp_(fexp2_(v * 2.88539008f) + 1.0f);
}

// pack 8 consecutive f32 into a v8f16 MFMA fragment slice
__device__ __forceinline__ hf8 pack8(const float* p) {
    union { hf2 h2[4]; hf8 h8; } u;
    u.h2[0] = __builtin_amdgcn_cvt_pkrtz(p[0], p[1]);
    u.h2[1] = __builtin_amdgcn_cvt_pkrtz(p[2], p[3]);
    u.h2[2] = __builtin_amdgcn_cvt_pkrtz(p[4], p[5]);
    u.h2[3] = __builtin_amdgcn_cvt_pkrtz(p[6], p[7]);
    return u.h8;
}

#define MFMA(D, A, B) D = __builtin_amdgcn_mfma_f32_16x16x32_f16(A, B, D, 0, 0, 0)

// Shared layout with CONTROLLED bank placement (R20 fix #1):
// h[t] reads hit banks 0-15 (base bank 0, q*16B offsets); z sits at bank 16
// (64 B pad after h) -> the divergent hsel read (m==0 lanes -> h, others -> z)
// touches DISJOINT bank sets. R19's 256-B separation aliased the same banks:
// SQ_LDS_BANK_CONFLICT = 6.7e7 (~128 cyc/block/step).
struct Smem {
    float  x[Tlen];       // 8192 B (64 x 128B)
    float  xh[Tlen];      // 8192 B
    __fp16 h[2][Hdim];    // 512 B, base bank 0
    __fp16 pad[32];       // 64 B  -> pushes z to bank 16
    __fp16 z[Hdim];       // 256 B of zeros (A rows 1-15)
};

// grid = 256 blocks (1 batch row each), block = 512 threads (8 waves).
// R20 = R19 (operand-inverted MFMA, 1 barrier/step, in-register h_old) plus:
//  (1) bank-disjoint z buffer (above);
//  (2) Wfc replicated across ALL 16 B-columns -> D3 row 0 holds xp in every
//      column, so each gate lane reads its own D3[0]. Removes the per-step
//      readfirstlane (VALU->SALU hazard) from the xp->cur->gates critical path.
// Layouts (R18/R19 HW-verified): A row = lane&15, k = c*32+(lane>>4)*8+j;
// D: col = lane&15, row = (lane>>4)*4 + reg.
__global__ __launch_bounds__(512, 2)
void rnn_imp_kernel(const float* __restrict__ x,     // [B, T] (I=1)
                    const float* __restrict__ Wih,   // [384]
                    const float* __restrict__ Whh,   // [384, 128] gate-major (r,z,n)
                    const float* __restrict__ bih,   // [384]
                    const float* __restrict__ bhh,   // [384]
                    const float* __restrict__ Wfc,   // [128]
                    const float* __restrict__ bfc,   // [1]
                    float* __restrict__ out_newin,   // [T, B]
                    float* __restrict__ out_pred)    // [B, T-1]
{
    __shared__ __align__(128) Smem sm;

    const int tid  = threadIdx.x;
    const int b    = blockIdx.x;
    const int wave = tid >> 6;
    const int lane = tid & 63;
    const int m    = lane & 15;      // A row / B,D column
    const int q    = lane >> 4;      // k-subchunk

    // stage x row (coalesced); zero h buffer 0 and the zero region
    for (int i = tid; i < Tlen; i += 512) sm.x[i] = x[b * Tlen + i];
    if (tid < Hdim) { sm.h[0][tid] = (__fp16)0.0f; sm.z[tid] = (__fp16)0.0f; }

    // ---- B fragments: W^T tiles (consumed only by MFMA -> AGPR-native) ----
    const int r0 = wave * 16 + m;            // unit row, gate r
    const int r1 = r0 + 128;                 // gate z
    const int r2 = r0 + 256;                 // gate n
    const int ko = q * 8;
    hf8 Br0, Br1, Br2, Br3, Bz0, Bz1, Bz2, Bz3,
        Bn0, Bn1, Bn2, Bn3, Bf0, Bf1, Bf2, Bf3;
    Br0 = pack8(Whh + r0 * Hdim + 0  + ko);  Br1 = pack8(Whh + r0 * Hdim + 32 + ko);
    Br2 = pack8(Whh + r0 * Hdim + 64 + ko);  Br3 = pack8(Whh + r0 * Hdim + 96 + ko);
    Bz0 = pack8(Whh + r1 * Hdim + 0  + ko);  Bz1 = pack8(Whh + r1 * Hdim + 32 + ko);
    Bz2 = pack8(Whh + r1 * Hdim + 64 + ko);  Bz3 = pack8(Whh + r1 * Hdim + 96 + ko);
    Bn0 = pack8(Whh + r2 * Hdim + 0  + ko);  Bn1 = pack8(Whh + r2 * Hdim + 32 + ko);
    Bn2 = pack8(Whh + r2 * Hdim + 64 + ko);  Bn3 = pack8(Whh + r2 * Hdim + 96 + ko);
    // Wfc in ALL columns (R20 fix #2): every lane's D3 row 0 = xp
    Bf0 = pack8(Wfc + 0  + ko);  Bf1 = pack8(Wfc + 32 + ko);
    Bf2 = pack8(Wfc + 64 + ko);  Bf3 = pack8(Wfc + 96 + ko);

    // gate constants for this wave's unit (valid on lanes 0-15)
    const int ug = wave * 16 + m;
    const float wih_r = Wih[ug], wih_z = Wih[ug + 128], wih_n = Wih[ug + 256];
    const float bb_r = bih[ug]       + bhh[ug];
    const float bb_z = bih[ug + 128] + bhh[ug + 128];
    const float bi_n = bih[ug + 256];
    const float bh_n = bhh[ug + 256];
    const float bfc0 = bfc[0];
    float h_old = 0.0f;

    __syncthreads();

#pragma unroll 1
    for (int t = 0; t < Tlen; ++t) {
        // A fragments: h on row 0 (m==0 lanes), zeros elsewhere — bank-disjoint
        const __fp16* hsel = (m == 0) ? sm.h[t & 1] : sm.z;
        const float4* hp = (const float4*)hsel;
        hf8 A0 = __builtin_bit_cast(hf8, hp[0 * 4 + q]);
        hf8 A1 = __builtin_bit_cast(hf8, hp[1 * 4 + q]);
        hf8 A2 = __builtin_bit_cast(hf8, hp[2 * 4 + q]);
        hf8 A3 = __builtin_bit_cast(hf8, hp[3 * 4 + q]);

        f32x4 D0 = {0.f, 0.f, 0.f, 0.f};    // ghr, units w*16+col
        f32x4 D1 = {0.f, 0.f, 0.f, 0.f};    // ghz
        f32x4 D2 = {0.f, 0.f, 0.f, 0.f};    // ghn
        f32x4 D3 = {0.f, 0.f, 0.f, 0.f};    // xp (row 0, every col)
        MFMA(D3, A0, Bf0); MFMA(D0, A0, Br0); MFMA(D1, A0, Bz0); MFMA(D2, A0, Bn0);
        MFMA(D3, A1, Bf1); MFMA(D0, A1, Br1); MFMA(D1, A1, Bz1); MFMA(D2, A1, Bn1);
        MFMA(D3, A2, Bf2); MFMA(D0, A2, Br2); MFMA(D1, A2, Bz2); MFMA(D2, A2, Bn2);
        MFMA(D3, A3, Bf3); MFMA(D0, A3, Br3); MFMA(D1, A3, Bz3); MFMA(D2, A3, Bn3);

        // gates on lanes 0-15 (row 0 = the gh/xp row), lane = unit-in-tile
        if (lane < 16) {
            float xp  = D3[0];
            float xh  = xp + bfc0;
            float xt  = sm.x[t];
            float cur = ((xt == 128.0f) && (t != 0)) ? xh : xt;

            float r  = sigmoidf_(wih_r * cur + bb_r + D0[0]);
            float z  = sigmoidf_(wih_z * cur + bb_z + D1[0]);
            float n  = tanhf_(wih_n * cur + bi_n + r * (D2[0] + bh_n));
            float hn = (1.0f - z) * n + z * h_old;
            h_old = hn;
            sm.h[(t + 1) & 1][ug] = (__fp16)hn;   // 16 consecutive b16/wave
            if (tid == 0) sm.xh[t] = xh;
        }
        __syncthreads();
    }

    // bulk flush; cur reconstructed from pristine x + xh
    for (int i = tid; i < Tlen; i += 512) {
        float xv = sm.x[i];
        float cv = ((xv == 128.0f) && (i != 0)) ? sm.xh[i] : xv;
        out_newin[i * Bsz + b] = cv;
    }
    for (int i = tid; i < Tlen - 1; i += 512)
        out_pred[b * (Tlen - 1) + i] = sm.xh[i + 1];
}

extern "C" void kernel_launch(void* const* d_in, const int* in_sizes, int n_in,
                              void* d_out, int out_size, void* d_ws, size_t ws_size,
                              hipStream_t stream) {
    const float* x   = (const float*)d_in[0];
    const float* Wih = (const float*)d_in[1];
    const float* Whh = (const float*)d_in[2];
    const float* bih = (const float*)d_in[3];
    const float* bhh = (const float*)d_in[4];
    const float* Wfc = (const float*)d_in[5];
    const float* bfc = (const float*)d_in[6];

    float* out_newin = (float*)d_out;                 // [T*B] = 524288
    float* out_pred  = out_newin + Tlen * Bsz;        // [B*(T-1)] = 524032

    rnn_imp_kernel<<<Bsz, 512, 0, stream>>>(x, Wih, Whh, bih, bhh, Wfc, bfc,
                                            out_newin, out_pred);
}

// Round 21
// 928.975 us; speedup vs baseline: 1.4824x; 1.1052x over previous
//
#include <hip/hip_runtime.h>

#define Bsz  256
#define Tlen 2048
#define Hdim 128

typedef __fp16 hf2 __attribute__((ext_vector_type(2)));
typedef __fp16 hf8 __attribute__((ext_vector_type(8)));
typedef float  f32x4 __attribute__((ext_vector_type(4)));

// Raw-HW transcendentals (VOP1, ~1 ulp). R12-verified win.
__device__ __forceinline__ float fexp2_(float x) {
    float r; asm("v_exp_f32 %0, %1" : "=v"(r) : "v"(x)); return r;
}
__device__ __forceinline__ float frcp_(float x) {
    float r; asm("v_rcp_f32 %0, %1" : "=v"(r) : "v"(x)); return r;
}
__device__ __forceinline__ float sigmoidf_(float v) {
    return frcp_(1.0f + fexp2_(v * -1.44269504f));
}
__device__ __forceinline__ float tanhf_(float v) {
    return 1.0f - 2.0f * frcp_(fexp2_(v * 2.88539008f) + 1.0f);
}

// pack 8 consecutive f32 into a v8f16 MFMA fragment slice
__device__ __forceinline__ hf8 pack8(const float* p) {
    union { hf2 h2[4]; hf8 h8; } u;
    u.h2[0] = __builtin_amdgcn_cvt_pkrtz(p[0], p[1]);
    u.h2[1] = __builtin_amdgcn_cvt_pkrtz(p[2], p[3]);
    u.h2[2] = __builtin_amdgcn_cvt_pkrtz(p[4], p[5]);
    u.h2[3] = __builtin_amdgcn_cvt_pkrtz(p[6], p[7]);
    return u.h8;
}
__device__ __forceinline__ hf8 bch8(float4 v) { return __builtin_bit_cast(hf8, v); }

#define MFMA(D, A, B) D = __builtin_amdgcn_mfma_f32_16x16x32_f16(A, B, D, 0, 0, 0)

struct Smem {
    float  x[Tlen];       // staged input row
    float  xh[Tlen];      // staged xh outputs
    __fp16 h[2][Hdim];    // double-buffered hidden state (f16)
};

// grid = 256 blocks (1 batch row each), block = 512 threads (8 waves).
// R21: uniform-A MFMA. EVERY row of A = h (not just row 0): since
// D[row][col] = dot(A[row], B[col]) = gh[col] identically for all rows, the
// only-row-0-read structure is preserved with NO zero rows. Wins:
//  (1) zbuf + divergent hsel deleted — A reads are 4 uniform-address b128s
//      (4 distinct 16B chunks, bank-disjoint, 16-way broadcast);
//  (2) D0..D3 reg 0 now valid on ALL lanes -> gate math runs unpredicated;
//      only the 16-lane h-write keeps an exec mask;
//  (3) xt load hoisted above the MFMAs (latency hidden under matrix work).
// Layouts (R18/R19/R20 HW-verified): B: lane l reg j = W[tile*16+(l&15)]
// [c*32+(l>>4)*8+j]; D: col = lane&15, row = (lane>>4)*4+reg.
__global__ __launch_bounds__(512, 2)
void rnn_imp_kernel(const float* __restrict__ x,     // [B, T] (I=1)
                    const float* __restrict__ Wih,   // [384]
                    const float* __restrict__ Whh,   // [384, 128] gate-major (r,z,n)
                    const float* __restrict__ bih,   // [384]
                    const float* __restrict__ bhh,   // [384]
                    const float* __restrict__ Wfc,   // [128]
                    const float* __restrict__ bfc,   // [1]
                    float* __restrict__ out_newin,   // [T, B]
                    float* __restrict__ out_pred)    // [B, T-1]
{
    __shared__ __align__(128) Smem sm;

    const int tid  = threadIdx.x;
    const int b    = blockIdx.x;
    const int wave = tid >> 6;
    const int lane = tid & 63;
    const int m    = lane & 15;      // B/D column = unit-in-tile
    const int q    = lane >> 4;      // k-subchunk

    // stage x row (coalesced); zero h buffer 0
    for (int i = tid; i < Tlen; i += 512) sm.x[i] = x[b * Tlen + i];
    if (tid < Hdim) sm.h[0][tid] = (__fp16)0.0f;

    // ---- B fragments: W^T tiles (consumed only by MFMA -> AGPR-native) ----
    const int r0 = wave * 16 + m;            // unit row, gate r
    const int r1 = r0 + 128;                 // gate z
    const int r2 = r0 + 256;                 // gate n
    const int ko = q * 8;
    hf8 Br0, Br1, Br2, Br3, Bz0, Bz1, Bz2, Bz3,
        Bn0, Bn1, Bn2, Bn3, Bf0, Bf1, Bf2, Bf3;
    Br0 = pack8(Whh + r0 * Hdim + 0  + ko);  Br1 = pack8(Whh + r0 * Hdim + 32 + ko);
    Br2 = pack8(Whh + r0 * Hdim + 64 + ko);  Br3 = pack8(Whh + r0 * Hdim + 96 + ko);
    Bz0 = pack8(Whh + r1 * Hdim + 0  + ko);  Bz1 = pack8(Whh + r1 * Hdim + 32 + ko);
    Bz2 = pack8(Whh + r1 * Hdim + 64 + ko);  Bz3 = pack8(Whh + r1 * Hdim + 96 + ko);
    Bn0 = pack8(Whh + r2 * Hdim + 0  + ko);  Bn1 = pack8(Whh + r2 * Hdim + 32 + ko);
    Bn2 = pack8(Whh + r2 * Hdim + 64 + ko);  Bn3 = pack8(Whh + r2 * Hdim + 96 + ko);
    // Wfc in ALL columns: every lane's D3 reg 0 = xp
    Bf0 = pack8(Wfc + 0  + ko);  Bf1 = pack8(Wfc + 32 + ko);
    Bf2 = pack8(Wfc + 64 + ko);  Bf3 = pack8(Wfc + 96 + ko);

    // gate constants for this lane's column unit (valid on all lanes)
    const int ug = wave * 16 + m;
    const float wih_r = Wih[ug], wih_z = Wih[ug + 128], wih_n = Wih[ug + 256];
    const float bb_r = bih[ug]       + bhh[ug];
    const float bb_z = bih[ug + 128] + bhh[ug + 128];
    const float bi_n = bih[ug + 256];
    const float bh_n = bhh[ug + 256];
    const float bfc0 = bfc[0];
    float h_old = 0.0f;                      // per-lane copy of unit ug's state

    __syncthreads();

#pragma unroll 1
    for (int t = 0; t < Tlen; ++t) {
        // xt early: LDS latency hides under the MFMA block
        float xt = sm.x[t];

        // A fragments: every row = h (uniform-address broadcast reads)
        const float4* hp = (const float4*)sm.h[t & 1];
        hf8 A0 = bch8(hp[0 * 4 + q]);
        hf8 A1 = bch8(hp[1 * 4 + q]);
        hf8 A2 = bch8(hp[2 * 4 + q]);
        hf8 A3 = bch8(hp[3 * 4 + q]);

        f32x4 D0 = {0.f, 0.f, 0.f, 0.f};    // ghr, units wave*16+col
        f32x4 D1 = {0.f, 0.f, 0.f, 0.f};    // ghz
        f32x4 D2 = {0.f, 0.f, 0.f, 0.f};    // ghn
        f32x4 D3 = {0.f, 0.f, 0.f, 0.f};    // xp (all rows/cols)
        MFMA(D3, A0, Bf0); MFMA(D0, A0, Br0); MFMA(D1, A0, Bz0); MFMA(D2, A0, Bn0);
        MFMA(D3, A1, Bf1); MFMA(D0, A1, Br1); MFMA(D1, A1, Bz1); MFMA(D2, A1, Bn1);
        MFMA(D3, A2, Bf2); MFMA(D0, A2, Br2); MFMA(D1, A2, Bz2); MFMA(D2, A2, Bn2);
        MFMA(D3, A3, Bf3); MFMA(D0, A3, Br3); MFMA(D1, A3, Bz3); MFMA(D2, A3, Bn3);

        // gates: unpredicated on all 64 lanes (q-copies compute identical hn)
        float xp  = D3[0];
        float xh  = xp + bfc0;
        float cur = ((xt == 128.0f) && (t != 0)) ? xh : xt;

        float r  = sigmoidf_(wih_r * cur + bb_r + D0[0]);
        float z  = sigmoidf_(wih_z * cur + bb_z + D1[0]);
        float n  = tanhf_(wih_n * cur + bi_n + r * (D2[0] + bh_n));
        float hn = (1.0f - z) * n + z * h_old;
        h_old = hn;

        if (lane < 16) sm.h[(t + 1) & 1][ug] = (__fp16)hn;
        if (tid == 0)  sm.xh[t] = xh;
        __syncthreads();
    }

    // bulk flush; cur reconstructed from pristine x + xh
    for (int i = tid; i < Tlen; i += 512) {
        float xv = sm.x[i];
        float cv = ((xv == 128.0f) && (i != 0)) ? sm.xh[i] : xv;
        out_newin[i * Bsz + b] = cv;
    }
    for (int i = tid; i < Tlen - 1; i += 512)
        out_pred[b * (Tlen - 1) + i] = sm.xh[i + 1];
}

extern "C" void kernel_launch(void* const* d_in, const int* in_sizes, int n_in,
                              void* d_out, int out_size, void* d_ws, size_t ws_size,
                              hipStream_t stream) {
    const float* x   = (const float*)d_in[0];
    const float* Wih = (const float*)d_in[1];
    const float* Whh = (const float*)d_in[2];
    const float* bih = (const float*)d_in[3];
    const float* bhh = (const float*)d_in[4];
    const float* Wfc = (const float*)d_in[5];
    const float* bfc = (const float*)d_in[6];

    float* out_newin = (float*)d_out;                 // [T*B] = 524288
    float* out_pred  = out_newin + Tlen * Bsz;        // [B*(T-1)] = 524032

    rnn_imp_kernel<<<Bsz, 512, 0, stream>>>(x, Wih, Whh, bih, bhh, Wfc, bfc,
                                            out_newin, out_pred);
}